// Round 1
// baseline (2476.326 us; speedup 1.0000x reference)
//
#include <hip/hip_runtime.h>

// Problem constants (from reference)
#define N_NODES 50000
#define N_EDGES (7 * N_NODES)   // 350000
#define BATCH 4
#define DIM 128
#define D4 (DIM / 4)            // 32 float4 chunks per row

// Kernel 1: out[b][n][d] = bias[d]  (out is poisoned before every timed call)
__global__ void init_out_kernel(float* __restrict__ out,
                                const float* __restrict__ bias) {
    int i = blockIdx.x * blockDim.x + threadIdx.x;      // float4 index
    const int total = BATCH * N_NODES * D4;             // 6.4M
    if (i >= total) return;
    int d4 = i & (D4 - 1);
    const float4* b4 = reinterpret_cast<const float4*>(bias);
    reinterpret_cast<float4*>(out)[i] = b4[d4];
}

// Kernel 2: one thread per (edge, d4). Loads edge meta + weight once,
// then for each batch: coalesced float4 gather of x[src], 4x fp32 atomicAdd
// into out[dst].
__global__ void edge_scatter_kernel(const float* __restrict__ x,
                                    const int* __restrict__ ei,
                                    const float* __restrict__ w,
                                    float* __restrict__ out) {
    int t = blockIdx.x * blockDim.x + threadIdx.x;
    const int total = N_EDGES * D4;                     // 11.2M
    if (t >= total) return;
    int e  = t >> 5;                                    // t / 32
    int d4 = t & 31;                                    // t % 32

    int src = ei[e];
    int dst = ei[N_EDGES + e];
    int typ = ei[2 * N_EDGES + e];

    const float4* x4 = reinterpret_cast<const float4*>(x);
    const float4* w4 = reinterpret_cast<const float4*>(w);

    float4 wv = w4[typ * D4 + d4];

    #pragma unroll
    for (int b = 0; b < BATCH; ++b) {
        float4 xv = x4[(size_t)(b * N_NODES + src) * D4 + d4];
        float* o = out + (size_t)(b * N_NODES + dst) * DIM + d4 * 4;
        atomicAdd(o + 0, xv.x * wv.x);
        atomicAdd(o + 1, xv.y * wv.y);
        atomicAdd(o + 2, xv.z * wv.z);
        atomicAdd(o + 3, xv.w * wv.w);
    }
}

extern "C" void kernel_launch(void* const* d_in, const int* in_sizes, int n_in,
                              void* d_out, int out_size, void* d_ws, size_t ws_size,
                              hipStream_t stream) {
    const float* x    = (const float*)d_in[0];   // (4, 50000, 128) f32
    const int*   ei   = (const int*)d_in[1];     // (3, 350000) i32
    const float* w    = (const float*)d_in[2];   // (1, 7, 128) f32
    const float* bias = (const float*)d_in[3];   // (1, 1, 128) f32
    float* out = (float*)d_out;                  // (4, 50000, 128) f32

    // Init out = bias
    {
        const int total = BATCH * N_NODES * D4;
        const int block = 256;
        const int grid = (total + block - 1) / block;
        init_out_kernel<<<grid, block, 0, stream>>>(out, bias);
    }
    // Scatter-add edges
    {
        const int total = N_EDGES * D4;
        const int block = 256;
        const int grid = (total + block - 1) / block;
        edge_scatter_kernel<<<grid, block, 0, stream>>>(x, ei, w, out);
    }
}

// Round 2
// 399.526 us; speedup vs baseline: 6.1982x; 6.1982x over previous
//
#include <hip/hip_runtime.h>

// Problem constants (from reference)
#define N_NODES 50000
#define N_EDGES (7 * N_NODES)   // 350000
#define BATCH 4
#define DIM 128
#define D4 (DIM / 4)            // 32 float4 chunks per row

#define SCAN_THREADS 1024
#define CHUNK ((N_NODES + SCAN_THREADS - 1) / SCAN_THREADS)  // 49

// ---- workspace layout (ints) ----
// counts  : [0, 50000)
// offsets : [50000, 100001)
// cursor  : [100001, 150001)  (round up to 150016 for alignment)
// meta    : [150016, 500016)
#define WS_COUNTS  0
#define WS_OFFSETS (N_NODES)
#define WS_CURSOR  (2 * N_NODES + 1)
#define WS_META    (3 * N_NODES + 16)

__global__ void zero_counts_kernel(int* __restrict__ counts) {
    int i = blockIdx.x * blockDim.x + threadIdx.x;
    if (i < N_NODES) counts[i] = 0;
}

__global__ void hist_kernel(const int* __restrict__ ei, int* __restrict__ counts) {
    int e = blockIdx.x * blockDim.x + threadIdx.x;
    if (e < N_EDGES) atomicAdd(&counts[ei[N_EDGES + e]], 1);
}

// Single-block exclusive scan of 50K counts (Hillis-Steele over 1024 partials).
__global__ void scan_kernel(const int* __restrict__ counts,
                            int* __restrict__ offsets,
                            int* __restrict__ cursor) {
    __shared__ int buf[2][SCAN_THREADS];
    int t = threadIdx.x;
    int begin = t * CHUNK;
    int end = begin + CHUNK;
    if (end > N_NODES) end = N_NODES;
    int sum = 0;
    for (int i = begin; i < end; ++i) sum += counts[i];
    buf[0][t] = sum;
    __syncthreads();
    int cur = 0;
    for (int off = 1; off < SCAN_THREADS; off <<= 1) {
        int v = buf[cur][t];
        if (t >= off) v += buf[cur][t - off];
        buf[cur ^ 1][t] = v;
        cur ^= 1;
        __syncthreads();
    }
    int incl = buf[cur][t];
    int run = incl - sum;   // exclusive prefix for this thread's chunk
    for (int i = begin; i < end; ++i) {
        offsets[i] = run;
        cursor[i]  = run;
        run += counts[i];
    }
    if (t == SCAN_THREADS - 1) offsets[N_NODES] = incl;  // grand total
}

// Scatter edges into dst-sorted order; meta = src | (typ << 20).
__global__ void scatter_kernel(const int* __restrict__ ei,
                               int* __restrict__ cursor,
                               int* __restrict__ meta) {
    int e = blockIdx.x * blockDim.x + threadIdx.x;
    if (e >= N_EDGES) return;
    int src = ei[e];
    int dst = ei[N_EDGES + e];
    int typ = ei[2 * N_EDGES + e];
    int pos = atomicAdd(&cursor[dst], 1);
    meta[pos] = src | (typ << 20);
}

// One thread per (node, d4). Accumulate all incoming edges in registers,
// write out once per batch (bias fused — no separate init pass).
__global__ void gather_kernel(const float* __restrict__ x,
                              const float* __restrict__ w,
                              const float* __restrict__ bias,
                              const int* __restrict__ offsets,
                              const int* __restrict__ meta,
                              float* __restrict__ out) {
    int t = blockIdx.x * blockDim.x + threadIdx.x;
    if (t >= N_NODES * D4) return;
    int n  = t >> 5;
    int d4 = t & 31;

    const float4* x4 = reinterpret_cast<const float4*>(x);
    const float4* w4 = reinterpret_cast<const float4*>(w);
    const float4* b4 = reinterpret_cast<const float4*>(bias);

    float4 bv = b4[d4];
    float4 a0 = bv, a1 = bv, a2 = bv, a3 = bv;

    int beg = offsets[n];
    int end = offsets[n + 1];
    for (int k = beg; k < end; ++k) {
        int m   = meta[k];
        int src = m & 0xFFFFF;
        int typ = m >> 20;
        float4 wv = w4[typ * D4 + d4];
        float4 v;
        v = x4[(size_t)(0 * N_NODES + src) * D4 + d4];
        a0.x += wv.x * v.x; a0.y += wv.y * v.y; a0.z += wv.z * v.z; a0.w += wv.w * v.w;
        v = x4[(size_t)(1 * N_NODES + src) * D4 + d4];
        a1.x += wv.x * v.x; a1.y += wv.y * v.y; a1.z += wv.z * v.z; a1.w += wv.w * v.w;
        v = x4[(size_t)(2 * N_NODES + src) * D4 + d4];
        a2.x += wv.x * v.x; a2.y += wv.y * v.y; a2.z += wv.z * v.z; a2.w += wv.w * v.w;
        v = x4[(size_t)(3 * N_NODES + src) * D4 + d4];
        a3.x += wv.x * v.x; a3.y += wv.y * v.y; a3.z += wv.z * v.z; a3.w += wv.w * v.w;
    }

    float4* o4 = reinterpret_cast<float4*>(out);
    o4[(size_t)(0 * N_NODES + n) * D4 + d4] = a0;
    o4[(size_t)(1 * N_NODES + n) * D4 + d4] = a1;
    o4[(size_t)(2 * N_NODES + n) * D4 + d4] = a2;
    o4[(size_t)(3 * N_NODES + n) * D4 + d4] = a3;
}

extern "C" void kernel_launch(void* const* d_in, const int* in_sizes, int n_in,
                              void* d_out, int out_size, void* d_ws, size_t ws_size,
                              hipStream_t stream) {
    const float* x    = (const float*)d_in[0];   // (4, 50000, 128) f32
    const int*   ei   = (const int*)d_in[1];     // (3, 350000) i32
    const float* w    = (const float*)d_in[2];   // (1, 7, 128) f32
    const float* bias = (const float*)d_in[3];   // (1, 1, 128) f32
    float* out = (float*)d_out;                  // (4, 50000, 128) f32

    int* ws      = (int*)d_ws;
    int* counts  = ws + WS_COUNTS;
    int* offsets = ws + WS_OFFSETS;
    int* cursor  = ws + WS_CURSOR;
    int* meta    = ws + WS_META;

    {   // zero the histogram (d_ws is poisoned before every call)
        const int grid = (N_NODES + 255) / 256;
        zero_counts_kernel<<<grid, 256, 0, stream>>>(counts);
    }
    {   // histogram of dst
        const int grid = (N_EDGES + 255) / 256;
        hist_kernel<<<grid, 256, 0, stream>>>(ei, counts);
    }
    {   // exclusive scan -> offsets, cursor
        scan_kernel<<<1, SCAN_THREADS, 0, stream>>>(counts, offsets, cursor);
    }
    {   // counting-sort edge meta by dst
        const int grid = (N_EDGES + 255) / 256;
        scatter_kernel<<<grid, 256, 0, stream>>>(ei, cursor, meta);
    }
    {   // gather + bias, single write of out
        const int total = N_NODES * D4;
        const int grid = (total + 255) / 256;
        gather_kernel<<<grid, 256, 0, stream>>>(x, w, bias, offsets, meta, out);
    }
}

// Round 3
// 277.452 us; speedup vs baseline: 8.9252x; 1.4400x over previous
//
#include <hip/hip_runtime.h>

// Problem constants (from reference)
#define N_NODES 50000
#define N_EDGES (7 * N_NODES)   // 350000
#define BATCH 4
#define DIM 128
#define D4 (DIM / 4)            // 32 float4 chunks per row
#define CAP 32                  // per-node bucket capacity (in-degree ~ Poisson(7))

// ---- workspace layout (ints) ----
#define WS_COUNTS  0                        // N_NODES counts
#define WS_OVFCNT  (N_NODES)                // 1 int (contiguous with counts for one memset)
#define WS_META    (N_NODES + 48)           // N_NODES*CAP packed src|typ<<20, 64B-aligned
#define WS_OVF     (WS_META + N_NODES*CAP)  // 2*N_EDGES worst-case overflow (m, dst) pairs
#define WS_TOTAL_INTS (WS_OVF + 2 * N_EDGES)

// ---------------- bucket path ----------------

// One thread per edge: append (src|typ) to dst's bucket; overflow -> list.
__global__ __launch_bounds__(256)
void bucket_scatter_kernel(const int* __restrict__ ei,
                           int* __restrict__ counts,
                           int* __restrict__ ovf_cnt,
                           int* __restrict__ meta,
                           int* __restrict__ ovf) {
    int e = blockIdx.x * 256 + threadIdx.x;
    if (e >= N_EDGES) return;
    int src = ei[e];
    int dst = ei[N_EDGES + e];
    int typ = ei[2 * N_EDGES + e];
    int m = src | (typ << 20);
    int pos = atomicAdd(&counts[dst], 1);
    if (pos < CAP) {
        meta[dst * CAP + pos] = m;
    } else {
        int oi = atomicAdd(ovf_cnt, 1);
        ovf[2 * oi]     = m;
        ovf[2 * oi + 1] = dst;
    }
}

// One thread per (batch, node, d4), batch-major for L2/L3 locality.
// 32 lanes of a node-group cooperatively preload the 32-slot bucket
// (one coalesced 128B read) and broadcast entries via shfl.
__global__ __launch_bounds__(256)
void gather_kernel(const float* __restrict__ x,
                   const float* __restrict__ w,
                   const float* __restrict__ bias,
                   const int* __restrict__ counts,
                   const int* __restrict__ meta,
                   float* __restrict__ out) {
    int i = blockIdx.x * 256 + threadIdx.x;       // exact: BATCH*N_NODES*D4 threads
    int b = i / (N_NODES * D4);
    int r = i - b * (N_NODES * D4);
    int n  = r >> 5;                              // node (uniform per 32-lane group)
    int d4 = r & 31;                              // == threadIdx.x & 31

    const float4* x4 = reinterpret_cast<const float4*>(x);
    const float4* w4 = reinterpret_cast<const float4*>(w);
    const float4* b4 = reinterpret_cast<const float4*>(bias);

    int cnt = counts[n];
    if (cnt > CAP) cnt = CAP;
    int mreg = meta[n * CAP + d4];                // slots >= cnt are garbage, never used

    float4 a = b4[d4];
    for (int k = 0; k < cnt; ++k) {
        int m   = __shfl(mreg, k, 32);
        int src = m & 0xFFFFF;
        int typ = m >> 20;
        float4 wv = w4[typ * D4 + d4];
        float4 xv = x4[(size_t)(b * N_NODES + src) * D4 + d4];
        a.x += wv.x * xv.x;
        a.y += wv.y * xv.y;
        a.z += wv.z * xv.z;
        a.w += wv.w * xv.w;
    }
    reinterpret_cast<float4*>(out)[(size_t)(b * N_NODES + n) * D4 + d4] = a;
}

// Rare overflow edges (deg > CAP): atomic adds, normally zero work.
__global__ __launch_bounds__(256)
void ovf_fix_kernel(const float* __restrict__ x,
                    const float* __restrict__ w,
                    const int* __restrict__ ovf_cnt,
                    const int* __restrict__ ovf,
                    float* __restrict__ out) {
    int total = *ovf_cnt;
    if (total <= 0) return;
    const float4* x4 = reinterpret_cast<const float4*>(x);
    const float4* w4 = reinterpret_cast<const float4*>(w);
    int stride = gridDim.x * blockDim.x;
    for (int t = blockIdx.x * blockDim.x + threadIdx.x; t < total * D4; t += stride) {
        int e  = t >> 5;
        int d4 = t & 31;
        int m   = ovf[2 * e];
        int dst = ovf[2 * e + 1];
        int src = m & 0xFFFFF;
        int typ = m >> 20;
        float4 wv = w4[typ * D4 + d4];
        #pragma unroll
        for (int b = 0; b < BATCH; ++b) {
            float4 xv = x4[(size_t)(b * N_NODES + src) * D4 + d4];
            float* o = out + (size_t)(b * N_NODES + dst) * DIM + d4 * 4;
            atomicAdd(o + 0, wv.x * xv.x);
            atomicAdd(o + 1, wv.y * xv.y);
            atomicAdd(o + 2, wv.z * xv.z);
            atomicAdd(o + 3, wv.w * xv.w);
        }
    }
}

// ---------------- fallback path (if ws too small): round-1 atomics ----------------

__global__ void init_out_kernel(float* __restrict__ out,
                                const float* __restrict__ bias) {
    int i = blockIdx.x * blockDim.x + threadIdx.x;
    const int total = BATCH * N_NODES * D4;
    if (i >= total) return;
    int d4 = i & (D4 - 1);
    reinterpret_cast<float4*>(out)[i] = reinterpret_cast<const float4*>(bias)[d4];
}

__global__ void edge_scatter_kernel(const float* __restrict__ x,
                                    const int* __restrict__ ei,
                                    const float* __restrict__ w,
                                    float* __restrict__ out) {
    int t = blockIdx.x * blockDim.x + threadIdx.x;
    const int total = N_EDGES * D4;
    if (t >= total) return;
    int e  = t >> 5;
    int d4 = t & 31;
    int src = ei[e];
    int dst = ei[N_EDGES + e];
    int typ = ei[2 * N_EDGES + e];
    const float4* x4 = reinterpret_cast<const float4*>(x);
    float4 wv = reinterpret_cast<const float4*>(w)[typ * D4 + d4];
    #pragma unroll
    for (int b = 0; b < BATCH; ++b) {
        float4 xv = x4[(size_t)(b * N_NODES + src) * D4 + d4];
        float* o = out + (size_t)(b * N_NODES + dst) * DIM + d4 * 4;
        atomicAdd(o + 0, xv.x * wv.x);
        atomicAdd(o + 1, xv.y * wv.y);
        atomicAdd(o + 2, xv.z * wv.z);
        atomicAdd(o + 3, xv.w * wv.w);
    }
}

extern "C" void kernel_launch(void* const* d_in, const int* in_sizes, int n_in,
                              void* d_out, int out_size, void* d_ws, size_t ws_size,
                              hipStream_t stream) {
    const float* x    = (const float*)d_in[0];   // (4, 50000, 128) f32
    const int*   ei   = (const int*)d_in[1];     // (3, 350000) i32
    const float* w    = (const float*)d_in[2];   // (1, 7, 128) f32
    const float* bias = (const float*)d_in[3];   // (1, 1, 128) f32
    float* out = (float*)d_out;                  // (4, 50000, 128) f32

    if (ws_size >= (size_t)WS_TOTAL_INTS * sizeof(int)) {
        int* ws      = (int*)d_ws;
        int* counts  = ws + WS_COUNTS;
        int* ovf_cnt = ws + WS_OVFCNT;
        int* meta    = ws + WS_META;
        int* ovf     = ws + WS_OVF;

        // zero counts + overflow counter (contiguous)
        hipMemsetAsync(counts, 0, (N_NODES + 1) * sizeof(int), stream);

        bucket_scatter_kernel<<<(N_EDGES + 255) / 256, 256, 0, stream>>>(
            ei, counts, ovf_cnt, meta, ovf);

        gather_kernel<<<BATCH * N_NODES * D4 / 256, 256, 0, stream>>>(
            x, w, bias, counts, meta, out);

        ovf_fix_kernel<<<64, 256, 0, stream>>>(x, w, ovf_cnt, ovf, out);
    } else {
        // fallback: atomic scatter (correct for any ws_size)
        init_out_kernel<<<(BATCH * N_NODES * D4 + 255) / 256, 256, 0, stream>>>(out, bias);
        edge_scatter_kernel<<<(N_EDGES * D4 + 255) / 256, 256, 0, stream>>>(x, ei, w, out);
    }
}